// Round 7
// baseline (462.266 us; speedup 1.0000x reference)
//
#include <hip/hip_runtime.h>
#include <hip/hip_bf16.h>
#include <hip/hip_cooperative_groups.h>

namespace cg = cooperative_groups;

// Problem constants
#define Bn 32
#define Cn 32
#define Ln 512
#define INTRA 1024
#define INTER 256
#define DCP 64
#define DDE 512
#define SCALEF 0.05f

typedef __attribute__((ext_vector_type(8))) short short8;
typedef __attribute__((ext_vector_type(4))) float floatx4;

__device__ __forceinline__ short bf16_of(float f) {
    union { float f; unsigned u; } v; v.f = f;
    unsigned r = (v.u + 0x7FFFu + ((v.u >> 16) & 1u)) >> 16;
    return (short)r;
}
__device__ __forceinline__ float f_of_bf16(short h) {
    union { unsigned u; float f; } v;
    v.u = ((unsigned)(unsigned short)h) << 16;
    return v.f;
}
__device__ __forceinline__ short8 cvt8(float4 a, float4 b) {
    short8 r;
    r[0] = bf16_of(a.x); r[1] = bf16_of(a.y); r[2] = bf16_of(a.z); r[3] = bf16_of(a.w);
    r[4] = bf16_of(b.x); r[5] = bf16_of(b.y); r[6] = bf16_of(b.z); r[7] = bf16_of(b.w);
    return r;
}

// ---------------------------------------------------------------------------
// Single cooperative mega-kernel: compress -> dn1 -> dn2 -> fuse with
// grid.sync() at stage boundaries. 512 blocks x 256 threads (2 blocks/CU).
// Shared memory: one 34816 B arena re-carved per stage.
// ---------------------------------------------------------------------------
__global__ __launch_bounds__(256, 2) void mega(
    const float* __restrict__ x_loc, const int* __restrict__ indices,
    const float* __restrict__ map_raw,
    const float* __restrict__ cW1, const float* __restrict__ cb1,
    const float* __restrict__ cW2, const float* __restrict__ cb2,
    const float* __restrict__ dW1, const float* __restrict__ db1,
    const float* __restrict__ dW2, const float* __restrict__ db2,
    const float* __restrict__ lamda1, const float* __restrict__ lamda2,
    short* __restrict__ M1T, short* __restrict__ HT, short* __restrict__ S16,
    float* __restrict__ out)
{
    cg::grid_group grid = cg::this_grid();

    __shared__ __align__(16) short smem[17408];   // 34816 B arena

    const int bid  = blockIdx.x;          // 0..511
    const int t    = threadIdx.x;
    const int w    = t >> 6;
    const int lane = t & 63;
    const int ln   = lane & 15;
    const int quad = lane >> 4;

    // =======================================================================
    // Stage A: compress.  c = bid>>4, m-tile = bid&15 (64 rows).
    //   T = relu(tile @ cW1^T + cb1); M1 = T @ cW2^T + cb2 -> M1T[c][d][i]
    // =======================================================================
    {
        const int c  = bid >> 4;
        const int m0 = (bid & 15) * 64;
        const float* A = map_raw + ((long)c * INTRA + m0) * INTER;

        short* Asb = smem;           // 64*72
        short* Bsb = smem + 4608;    // 64*72
        short* Tsb = smem + 9216;    // 64*72

        const int sr = t >> 2, sk = (t & 3) * 16;
        const float* ap = A + sr * INTER + sk;
        const float* bp = cW1 + sr * INTER + sk;

        floatx4 acc[4] = {};
        float4 a0 = *(const float4*)(ap),     a1 = *(const float4*)(ap + 4);
        float4 a2 = *(const float4*)(ap + 8), a3 = *(const float4*)(ap + 12);
        float4 b0 = *(const float4*)(bp),     b1 = *(const float4*)(bp + 4);
        float4 b2 = *(const float4*)(bp + 8), b3 = *(const float4*)(bp + 12);

        for (int k0 = 0; k0 < INTER; k0 += 64) {
            __syncthreads();
            *(short8*)&Asb[sr * 72 + sk]     = cvt8(a0, a1);
            *(short8*)&Asb[sr * 72 + sk + 8] = cvt8(a2, a3);
            *(short8*)&Bsb[sr * 72 + sk]     = cvt8(b0, b1);
            *(short8*)&Bsb[sr * 72 + sk + 8] = cvt8(b2, b3);
            __syncthreads();
            const int kn = k0 + 64;
            if (kn < INTER) {
                a0 = *(const float4*)(ap + kn);     a1 = *(const float4*)(ap + kn + 4);
                a2 = *(const float4*)(ap + kn + 8); a3 = *(const float4*)(ap + kn + 12);
                b0 = *(const float4*)(bp + kn);     b1 = *(const float4*)(bp + kn + 4);
                b2 = *(const float4*)(bp + kn + 8); b3 = *(const float4*)(bp + kn + 12);
            }
            #pragma unroll
            for (int kc = 0; kc < 2; ++kc) {
                short8 af = *(const short8*)&Asb[(w * 16 + ln) * 72 + kc * 32 + quad * 8];
                #pragma unroll
                for (int nt = 0; nt < 4; ++nt) {
                    short8 bf = *(const short8*)&Bsb[(nt * 16 + ln) * 72 + kc * 32 + quad * 8];
                    acc[nt] = __builtin_amdgcn_mfma_f32_16x16x32_bf16(af, bf, acc[nt], 0, 0, 0);
                }
            }
        }
        __syncthreads();

        #pragma unroll
        for (int nt = 0; nt < 4; ++nt) {
            const int n = nt * 16 + ln;
            const float b = cb1[n];
            #pragma unroll
            for (int r = 0; r < 4; ++r)
                Tsb[(w * 16 + quad * 4 + r) * 72 + n] = bf16_of(fmaxf(acc[nt][r] + b, 0.f));
        }
        __syncthreads();

        floatx4 acc2[4] = {};
        #pragma unroll
        for (int ks = 0; ks < 2; ++ks) {
            short8 af = *(const short8*)&Tsb[(w * 16 + ln) * 72 + ks * 32 + quad * 8];
            #pragma unroll
            for (int nt = 0; nt < 4; ++nt) {
                const float* wp = cW2 + (nt * 16 + ln) * 64 + ks * 32 + quad * 8;
                short8 bf = cvt8(*(const float4*)wp, *(const float4*)(wp + 4));
                acc2[nt] = __builtin_amdgcn_mfma_f32_16x16x32_bf16(af, bf, acc2[nt], 0, 0, 0);
            }
        }

        short* outp = M1T + (long)c * 64 * INTRA;
        #pragma unroll
        for (int nt = 0; nt < 4; ++nt) {
            const int n = nt * 16 + ln;
            const float b = cb2[n];
            short t0 = bf16_of(acc2[nt][0] + b);
            short t1 = bf16_of(acc2[nt][1] + b);
            short t2 = bf16_of(acc2[nt][2] + b);
            short t3 = bf16_of(acc2[nt][3] + b);
            *(short4*)(outp + (long)n * INTRA + m0 + w * 16 + quad * 4) =
                make_short4(t0, t1, t2, t3);
        }
    }

    __threadfence();
    grid.sync();

    // =======================================================================
    // Stage B: denoise-1.  c = bid>>4, h-tile = bid&15 (32 rows). BK=128.
    //   HT[c][d][h] = relu(dW1 @ M1[c] + db1)
    // =======================================================================
    {
        const int c  = bid >> 4;
        const int h0 = (bid & 15) * 32;

        short* Asb = smem;           // 32*136 = 4352
        short* Bsb = smem + 4352;    // 64*136 = 8704

        const int ar = t >> 3, ak = (t & 7) * 16;
        const int br = t >> 2, bk = (t & 3) * 32;

        const float* Ap = dW1 + (long)(h0 + ar) * INTRA + ak;
        const short* Bp = M1T + (long)c * 64 * INTRA + (long)br * INTRA + bk;

        floatx4 acc[2] = {};
        float4 fa0 = *(const float4*)(Ap),     fa1 = *(const float4*)(Ap + 4);
        float4 fa2 = *(const float4*)(Ap + 8), fa3 = *(const float4*)(Ap + 12);
        short8 sb0 = *(const short8*)(Bp),      sb1 = *(const short8*)(Bp + 8);
        short8 sb2 = *(const short8*)(Bp + 16), sb3 = *(const short8*)(Bp + 24);

        const int mb = (w & 1) * 16;
        const int nb = (w >> 1) * 2;

        for (int k0 = 0; k0 < INTRA; k0 += 128) {
            __syncthreads();
            *(short8*)&Asb[ar * 136 + ak]      = cvt8(fa0, fa1);
            *(short8*)&Asb[ar * 136 + ak + 8]  = cvt8(fa2, fa3);
            *(short8*)&Bsb[br * 136 + bk]      = sb0;
            *(short8*)&Bsb[br * 136 + bk + 8]  = sb1;
            *(short8*)&Bsb[br * 136 + bk + 16] = sb2;
            *(short8*)&Bsb[br * 136 + bk + 24] = sb3;
            __syncthreads();
            const int kn = k0 + 128;
            if (kn < INTRA) {
                fa0 = *(const float4*)(Ap + kn);     fa1 = *(const float4*)(Ap + kn + 4);
                fa2 = *(const float4*)(Ap + kn + 8); fa3 = *(const float4*)(Ap + kn + 12);
                sb0 = *(const short8*)(Bp + kn);      sb1 = *(const short8*)(Bp + kn + 8);
                sb2 = *(const short8*)(Bp + kn + 16); sb3 = *(const short8*)(Bp + kn + 24);
            }
            #pragma unroll
            for (int kc = 0; kc < 4; ++kc) {
                short8 af  = *(const short8*)&Asb[(mb + ln) * 136 + kc * 32 + quad * 8];
                short8 bf0 = *(const short8*)&Bsb[((nb + 0) * 16 + ln) * 136 + kc * 32 + quad * 8];
                short8 bf1 = *(const short8*)&Bsb[((nb + 1) * 16 + ln) * 136 + kc * 32 + quad * 8];
                acc[0] = __builtin_amdgcn_mfma_f32_16x16x32_bf16(af, bf0, acc[0], 0, 0, 0);
                acc[1] = __builtin_amdgcn_mfma_f32_16x16x32_bf16(af, bf1, acc[1], 0, 0, 0);
            }
        }

        float bm[4];
        #pragma unroll
        for (int r = 0; r < 4; ++r) bm[r] = db1[h0 + mb + quad * 4 + r];

        short* outp = HT + (long)c * 64 * DDE;
        #pragma unroll
        for (int j = 0; j < 2; ++j) {
            const int d = (nb + j) * 16 + ln;
            float v0 = fmaxf(acc[j][0] + bm[0], 0.f);
            float v1 = fmaxf(acc[j][1] + bm[1], 0.f);
            float v2 = fmaxf(acc[j][2] + bm[2], 0.f);
            float v3 = fmaxf(acc[j][3] + bm[3], 0.f);
            *(short4*)(outp + (long)d * DDE + h0 + mb + quad * 4) =
                make_short4(bf16_of(v0), bf16_of(v1), bf16_of(v2), bf16_of(v3));
        }
    }

    __threadfence();
    grid.sync();

    // =======================================================================
    // Stage C: denoise-2.  c = bid>>4, i-tile = bid&15 (64 i). BK=128.
    //   S16[c][i][d] = dW2 @ H[c] + db2   (m=d, n=i)
    // =======================================================================
    {
        const int c  = bid >> 4;
        const int n0 = (bid & 15) * 64;

        short* Asb = smem;           // 64*136 = 8704
        short* Bsb = smem + 8704;    // 64*136 = 8704

        const int ar = t >> 2, ak = (t & 3) * 32;

        const short* Ap = HT + (long)c * 64 * DDE + (long)ar * DDE + ak;
        const float* Bp = dW2 + (long)(n0 + ar) * DDE + ak;

        floatx4 acc[4] = {};
        short8 sa0 = *(const short8*)(Ap),      sa1 = *(const short8*)(Ap + 8);
        short8 sa2 = *(const short8*)(Ap + 16), sa3 = *(const short8*)(Ap + 24);
        float4 fb0 = *(const float4*)(Bp),      fb1 = *(const float4*)(Bp + 4);
        float4 fb2 = *(const float4*)(Bp + 8),  fb3 = *(const float4*)(Bp + 12);
        float4 fb4 = *(const float4*)(Bp + 16), fb5 = *(const float4*)(Bp + 20);
        float4 fb6 = *(const float4*)(Bp + 24), fb7 = *(const float4*)(Bp + 28);

        for (int k0 = 0; k0 < DDE; k0 += 128) {
            __syncthreads();
            *(short8*)&Asb[ar * 136 + ak]      = sa0;
            *(short8*)&Asb[ar * 136 + ak + 8]  = sa1;
            *(short8*)&Asb[ar * 136 + ak + 16] = sa2;
            *(short8*)&Asb[ar * 136 + ak + 24] = sa3;
            *(short8*)&Bsb[ar * 136 + ak]      = cvt8(fb0, fb1);
            *(short8*)&Bsb[ar * 136 + ak + 8]  = cvt8(fb2, fb3);
            *(short8*)&Bsb[ar * 136 + ak + 16] = cvt8(fb4, fb5);
            *(short8*)&Bsb[ar * 136 + ak + 24] = cvt8(fb6, fb7);
            __syncthreads();
            const int kn = k0 + 128;
            if (kn < DDE) {
                sa0 = *(const short8*)(Ap + kn);      sa1 = *(const short8*)(Ap + kn + 8);
                sa2 = *(const short8*)(Ap + kn + 16); sa3 = *(const short8*)(Ap + kn + 24);
                fb0 = *(const float4*)(Bp + kn);      fb1 = *(const float4*)(Bp + kn + 4);
                fb2 = *(const float4*)(Bp + kn + 8);  fb3 = *(const float4*)(Bp + kn + 12);
                fb4 = *(const float4*)(Bp + kn + 16); fb5 = *(const float4*)(Bp + kn + 20);
                fb6 = *(const float4*)(Bp + kn + 24); fb7 = *(const float4*)(Bp + kn + 28);
            }
            #pragma unroll
            for (int kc = 0; kc < 4; ++kc) {
                short8 af = *(const short8*)&Asb[(w * 16 + ln) * 136 + kc * 32 + quad * 8];
                #pragma unroll
                for (int nt = 0; nt < 4; ++nt) {
                    short8 bf = *(const short8*)&Bsb[(nt * 16 + ln) * 136 + kc * 32 + quad * 8];
                    acc[nt] = __builtin_amdgcn_mfma_f32_16x16x32_bf16(af, bf, acc[nt], 0, 0, 0);
                }
            }
        }

        const int d0 = w * 16 + quad * 4;
        #pragma unroll
        for (int nt = 0; nt < 4; ++nt) {
            const int i = n0 + nt * 16 + ln;
            const float bb = db2[i];
            short t0 = bf16_of(acc[nt][0] + bb);
            short t1 = bf16_of(acc[nt][1] + bb);
            short t2 = bf16_of(acc[nt][2] + bb);
            short t3 = bf16_of(acc[nt][3] + bb);
            *(short4*)(S16 + ((long)c * INTRA + i) * DCP + d0) = make_short4(t0, t1, t2, t3);
        }
    }

    __threadfence();
    grid.sync();

    // =======================================================================
    // Stage D: fuse.  2 (b,c) pairs per block: p = bid, bid+512.
    // =======================================================================
    {
        float* xs  = (float*)smem;                    // 512 f
        int*   idx = (int*)(smem + 1024);             // 512 i
        float (*red)[DCP] = (float(*)[DCP])(smem + 2048);  // 4*64 f
        short* wbf = smem + 2560;                     // 64 bf16
        float* ob  = (float*)(smem + 2624);           // 512 f

        const int r  = lane >> 4;
        const int dg = lane & 15;

        #pragma unroll
        for (int pp = 0; pp < 2; ++pp) {
            const int p = bid + pp * 512;
            const int c = p & 31;
            const int b = p >> 5;

            const float* xp = x_loc + ((long)b * Cn + c) * Ln;
            const int*   ip = indices + (long)b * Ln;
            ((float2*)xs)[t] = ((const float2*)xp)[t];
            ((int2*)idx)[t]  = ((const int2*)ip)[t];
            __syncthreads();

            const short* Sc = S16 + (long)c * INTRA * DCP;

            // Phase 1: scores[d]
            float s0 = 0.f, s1 = 0.f, s2 = 0.f, s3 = 0.f;
            #pragma unroll 4
            for (int i = 0; i < 32; ++i) {
                const int lbase = w * 128 + i * 4;
                const int row   = idx[lbase + r];
                short4 g = *(const short4*)(Sc + (long)row * DCP + dg * 4);
                const float x = xs[lbase + r];
                s0 += fabsf(x - f_of_bf16(g.x));
                s1 += fabsf(x - f_of_bf16(g.y));
                s2 += fabsf(x - f_of_bf16(g.z));
                s3 += fabsf(x - f_of_bf16(g.w));
            }
            s0 += __shfl_xor(s0, 16); s0 += __shfl_xor(s0, 32);
            s1 += __shfl_xor(s1, 16); s1 += __shfl_xor(s1, 32);
            s2 += __shfl_xor(s2, 16); s2 += __shfl_xor(s2, 32);
            s3 += __shfl_xor(s3, 16); s3 += __shfl_xor(s3, 32);
            if (lane < 16) {
                red[w][dg * 4 + 0] = s0;
                red[w][dg * 4 + 1] = s1;
                red[w][dg * 4 + 2] = s2;
                red[w][dg * 4 + 3] = s3;
            }
            __syncthreads();

            if (t < DCP) {
                float sc = red[0][t] + red[1][t] + red[2][t] + red[3][t];
                sc = -sc * (SCALEF * 0.044194173824159216f);
                float m = sc;
                #pragma unroll
                for (int o = 32; o > 0; o >>= 1) m = fmaxf(m, __shfl_xor(m, o));
                float e = __expf(sc - m);
                float ssum = e;
                #pragma unroll
                for (int o = 32; o > 0; o >>= 1) ssum += __shfl_xor(ssum, o);
                wbf[t] = bf16_of(e / ssum);
            }
            __syncthreads();

            // Phase 2: MFMA matvec
            short8 bw0 = *(const short8*)&wbf[quad * 8];
            short8 bw1 = *(const short8*)&wbf[32 + quad * 8];

            #pragma unroll
            for (int mt = 0; mt < 8; ++mt) {
                const int mrow = w * 128 + mt * 16 + ln;
                const short* rp = Sc + (long)idx[mrow] * DCP;
                short8 a0 = *(const short8*)(rp + quad * 8);
                short8 a1 = *(const short8*)(rp + 32 + quad * 8);
                floatx4 acc = {};
                acc = __builtin_amdgcn_mfma_f32_16x16x32_bf16(a0, bw0, acc, 0, 0, 0);
                acc = __builtin_amdgcn_mfma_f32_16x16x32_bf16(a1, bw1, acc, 0, 0, 0);
                if (ln == 0) {
                    const int l0 = w * 128 + mt * 16 + quad * 4;
                    ob[l0 + 0] = acc[0];
                    ob[l0 + 1] = acc[1];
                    ob[l0 + 2] = acc[2];
                    ob[l0 + 3] = acc[3];
                }
            }
            __syncthreads();

            // Final blend, coalesced
            const float lam1 = 1.f / (1.f + __expf(-lamda1[c]));
            #pragma unroll
            for (int j = 0; j < 2; ++j) {
                const int l = t + j * 256;
                const float lam = lam1 * (1.f / (1.f + __expf(-lamda2[l])));
                out[((long)b * Cn + c) * Ln + l] = ob[l] * lam + xs[l] * (1.f - lam);
            }
            __syncthreads();   // smem reused by next pair
        }
    }
}

// ---------------------------------------------------------------------------
// Launch: ONE cooperative dispatch.
// ---------------------------------------------------------------------------
extern "C" void kernel_launch(void* const* d_in, const int* in_sizes, int n_in,
                              void* d_out, int out_size, void* d_ws, size_t ws_size,
                              hipStream_t stream)
{
    const float* x_loc   = (const float*)d_in[0];
    const int*   indices = (const int*)d_in[1];
    const float* map_raw = (const float*)d_in[2];
    const float* cW1     = (const float*)d_in[3];
    const float* cb1     = (const float*)d_in[4];
    const float* cW2     = (const float*)d_in[5];
    const float* cb2     = (const float*)d_in[6];
    const float* dW1     = (const float*)d_in[7];
    const float* db1     = (const float*)d_in[8];
    const float* dW2     = (const float*)d_in[9];
    const float* db2     = (const float*)d_in[10];
    const float* lamda1  = (const float*)d_in[11];
    const float* lamda2  = (const float*)d_in[12];
    float* out = (float*)d_out;

    short* wsS = (short*)d_ws;
    short* M1T = wsS;                 // 32*64*1024 bf16
    short* HT  = M1T + 2097152;       // 32*64*512
    short* S16 = HT + 1048576;        // 32*1024*64

    void* args[] = {
        (void*)&x_loc, (void*)&indices, (void*)&map_raw,
        (void*)&cW1, (void*)&cb1, (void*)&cW2, (void*)&cb2,
        (void*)&dW1, (void*)&db1, (void*)&dW2, (void*)&db2,
        (void*)&lamda1, (void*)&lamda2,
        (void*)&M1T, (void*)&HT, (void*)&S16, (void*)&out
    };

    hipLaunchCooperativeKernel((void*)mega, dim3(512), dim3(256),
                               args, 0, stream);
}

// Round 8
// 152.831 us; speedup vs baseline: 3.0247x; 3.0247x over previous
//
#include <hip/hip_runtime.h>
#include <hip/hip_bf16.h>

// Problem constants
#define Bn 32
#define Cn 32
#define Ln 512
#define INTRA 1024
#define INTER 256
#define DCP 64
#define DDE 512
#define SCALEF 0.05f

typedef __attribute__((ext_vector_type(8))) short short8;
typedef __attribute__((ext_vector_type(4))) float floatx4;

__device__ __forceinline__ short bf16_of(float f) {
    union { float f; unsigned u; } v; v.f = f;
    unsigned r = (v.u + 0x7FFFu + ((v.u >> 16) & 1u)) >> 16;
    return (short)r;
}
__device__ __forceinline__ float f_of_bf16(short h) {
    union { unsigned u; float f; } v;
    v.u = ((unsigned)(unsigned short)h) << 16;
    return v.f;
}
__device__ __forceinline__ short8 cvt8(float4 a, float4 b) {
    short8 r;
    r[0] = bf16_of(a.x); r[1] = bf16_of(a.y); r[2] = bf16_of(a.z); r[3] = bf16_of(a.w);
    r[4] = bf16_of(b.x); r[5] = bf16_of(b.y); r[6] = bf16_of(b.z); r[7] = bf16_of(b.w);
    return r;
}

// ---------------------------------------------------------------------------
// compress: 32-row m-tiles, BK=128 (2 K-iters). Grid (32,32)=1024 blocks,
// 4 blocks/CU. LDS 30.7 KB. fp32 A and cW1 converted in-staging.
// Output M1T[c][d][i] bf16.
// ---------------------------------------------------------------------------
__global__ __launch_bounds__(256) void compress_fused(
    const float* __restrict__ map_raw, const float* __restrict__ cW1,
    const float* __restrict__ cb1, const float* __restrict__ cW2,
    const float* __restrict__ cb2, short* __restrict__ M1T)
{
    const int c  = blockIdx.y;
    const int m0 = blockIdx.x * 32;
    const float* A = map_raw + ((long)c * INTRA + m0) * INTER;

    __shared__ short Asb[32 * 136];
    __shared__ short Bsb[64 * 136];
    __shared__ short Tsb[32 * 72];

    const int t = threadIdx.x, w = t >> 6, lane = t & 63;
    const int ln = lane & 15, quad = lane >> 4;
    const int ar = t >> 3, ak = (t & 7) * 16;   // A: 32 rows x 128, 16 f/thr
    const int br = t >> 2, bk = (t & 3) * 32;   // B: 64 rows x 128, 32 f/thr

    const float* ap = A + (long)ar * INTER + ak;
    const float* bp = cW1 + (long)br * INTER + bk;

    const int mb = (w & 1) * 16;
    const int nb = (w >> 1) * 2;

    floatx4 acc[2] = {};
    float4 fa0 = *(const float4*)(ap),      fa1 = *(const float4*)(ap + 4);
    float4 fa2 = *(const float4*)(ap + 8),  fa3 = *(const float4*)(ap + 12);
    float4 fb0 = *(const float4*)(bp),      fb1 = *(const float4*)(bp + 4);
    float4 fb2 = *(const float4*)(bp + 8),  fb3 = *(const float4*)(bp + 12);
    float4 fb4 = *(const float4*)(bp + 16), fb5 = *(const float4*)(bp + 20);
    float4 fb6 = *(const float4*)(bp + 24), fb7 = *(const float4*)(bp + 28);

    for (int k0 = 0; k0 < INTER; k0 += 128) {
        __syncthreads();
        *(short8*)&Asb[ar * 136 + ak]      = cvt8(fa0, fa1);
        *(short8*)&Asb[ar * 136 + ak + 8]  = cvt8(fa2, fa3);
        *(short8*)&Bsb[br * 136 + bk]      = cvt8(fb0, fb1);
        *(short8*)&Bsb[br * 136 + bk + 8]  = cvt8(fb2, fb3);
        *(short8*)&Bsb[br * 136 + bk + 16] = cvt8(fb4, fb5);
        *(short8*)&Bsb[br * 136 + bk + 24] = cvt8(fb6, fb7);
        __syncthreads();
        const int kn = k0 + 128;
        if (kn < INTER) {
            fa0 = *(const float4*)(ap + kn);      fa1 = *(const float4*)(ap + kn + 4);
            fa2 = *(const float4*)(ap + kn + 8);  fa3 = *(const float4*)(ap + kn + 12);
            fb0 = *(const float4*)(bp + kn);      fb1 = *(const float4*)(bp + kn + 4);
            fb2 = *(const float4*)(bp + kn + 8);  fb3 = *(const float4*)(bp + kn + 12);
            fb4 = *(const float4*)(bp + kn + 16); fb5 = *(const float4*)(bp + kn + 20);
            fb6 = *(const float4*)(bp + kn + 24); fb7 = *(const float4*)(bp + kn + 28);
        }
        #pragma unroll
        for (int kc = 0; kc < 4; ++kc) {
            short8 af  = *(const short8*)&Asb[(mb + ln) * 136 + kc * 32 + quad * 8];
            short8 bf0 = *(const short8*)&Bsb[((nb + 0) * 16 + ln) * 136 + kc * 32 + quad * 8];
            short8 bf1 = *(const short8*)&Bsb[((nb + 1) * 16 + ln) * 136 + kc * 32 + quad * 8];
            acc[0] = __builtin_amdgcn_mfma_f32_16x16x32_bf16(af, bf0, acc[0], 0, 0, 0);
            acc[1] = __builtin_amdgcn_mfma_f32_16x16x32_bf16(af, bf1, acc[1], 0, 0, 0);
        }
    }

    // T = relu(acc + cb1): rows mb+quad*4+r, cols (nb+j)*16+ln (disjoint per wave)
    #pragma unroll
    for (int j = 0; j < 2; ++j) {
        const int n = (nb + j) * 16 + ln;
        const float b = cb1[n];
        #pragma unroll
        for (int r = 0; r < 4; ++r)
            Tsb[(mb + quad * 4 + r) * 72 + n] = bf16_of(fmaxf(acc[j][r] + b, 0.f));
    }
    __syncthreads();

    // Phase 2: M1 = T @ cW2^T; B-frags fp32 cW2 direct from global, cvt.
    floatx4 acc2[2] = {};
    #pragma unroll
    for (int ks = 0; ks < 2; ++ks) {
        short8 af = *(const short8*)&Tsb[(mb + ln) * 72 + ks * 32 + quad * 8];
        #pragma unroll
        for (int j = 0; j < 2; ++j) {
            const float* wp = cW2 + ((nb + j) * 16 + ln) * 64 + ks * 32 + quad * 8;
            short8 bf = cvt8(*(const float4*)wp, *(const float4*)(wp + 4));
            acc2[j] = __builtin_amdgcn_mfma_f32_16x16x32_bf16(af, bf, acc2[j], 0, 0, 0);
        }
    }

    // store M1T[c][d][i]: d=(nb+j)*16+ln, i = m0+mb+quad*4 .. +3
    short* outp = M1T + (long)c * 64 * INTRA;
    const int is = m0 + mb + quad * 4;
    #pragma unroll
    for (int j = 0; j < 2; ++j) {
        const int n = (nb + j) * 16 + ln;
        const float b = cb2[n];
        short t0 = bf16_of(acc2[j][0] + b);
        short t1 = bf16_of(acc2[j][1] + b);
        short t2 = bf16_of(acc2[j][2] + b);
        short t3 = bf16_of(acc2[j][3] + b);
        *(short4*)(outp + (long)n * INTRA + is) = make_short4(t0, t1, t2, t3);
    }
}

// ---------------------------------------------------------------------------
// denoise-1: 16-row h-tiles, BK=128 (8 iters). Grid (32,32)=1024 blocks,
// 4 blocks/CU. LDS 21.8 KB.  HT[c][d][h] = relu(dW1 @ M1[c] + db1)
// ---------------------------------------------------------------------------
__global__ __launch_bounds__(256) void gemm_dn1(
    const float* __restrict__ dW1, const short* __restrict__ M1T,
    const float* __restrict__ db1, short* __restrict__ HT)
{
    const int c  = blockIdx.y;
    const int h0 = blockIdx.x * 16;

    __shared__ short Asb[16 * 136];
    __shared__ short Bsb[64 * 136];

    const int t = threadIdx.x, w = t >> 6, lane = t & 63;
    const int ln = lane & 15, quad = lane >> 4;
    const int ar = t >> 4, ak = (t & 15) * 8;   // A: 16 rows x 128, 8 f/thr
    const int br = t >> 2, bk = (t & 3) * 32;   // B: 64 rows x 128, 32 sh/thr

    const float* Ap = dW1 + (long)(h0 + ar) * INTRA + ak;
    const short* Bp = M1T + (long)c * 64 * INTRA + (long)br * INTRA + bk;

    floatx4 acc = {};
    float4 fa0 = *(const float4*)(Ap), fa1 = *(const float4*)(Ap + 4);
    short8 sb0 = *(const short8*)(Bp),      sb1 = *(const short8*)(Bp + 8);
    short8 sb2 = *(const short8*)(Bp + 16), sb3 = *(const short8*)(Bp + 24);

    for (int k0 = 0; k0 < INTRA; k0 += 128) {
        __syncthreads();
        *(short8*)&Asb[ar * 136 + ak]      = cvt8(fa0, fa1);
        *(short8*)&Bsb[br * 136 + bk]      = sb0;
        *(short8*)&Bsb[br * 136 + bk + 8]  = sb1;
        *(short8*)&Bsb[br * 136 + bk + 16] = sb2;
        *(short8*)&Bsb[br * 136 + bk + 24] = sb3;
        __syncthreads();
        const int kn = k0 + 128;
        if (kn < INTRA) {
            fa0 = *(const float4*)(Ap + kn);      fa1 = *(const float4*)(Ap + kn + 4);
            sb0 = *(const short8*)(Bp + kn);      sb1 = *(const short8*)(Bp + kn + 8);
            sb2 = *(const short8*)(Bp + kn + 16); sb3 = *(const short8*)(Bp + kn + 24);
        }
        #pragma unroll
        for (int kc = 0; kc < 4; ++kc) {
            short8 af = *(const short8*)&Asb[ln * 136 + kc * 32 + quad * 8];
            short8 bf = *(const short8*)&Bsb[(w * 16 + ln) * 136 + kc * 32 + quad * 8];
            acc = __builtin_amdgcn_mfma_f32_16x16x32_bf16(af, bf, acc, 0, 0, 0);
        }
    }

    float bm[4];
    #pragma unroll
    for (int r = 0; r < 4; ++r) bm[r] = db1[h0 + quad * 4 + r];

    // C[m=h][n=d]: d = w*16+ln, h = h0 + quad*4 + r
    const int d = w * 16 + ln;
    float v0 = fmaxf(acc[0] + bm[0], 0.f);
    float v1 = fmaxf(acc[1] + bm[1], 0.f);
    float v2 = fmaxf(acc[2] + bm[2], 0.f);
    float v3 = fmaxf(acc[3] + bm[3], 0.f);
    *(short4*)(HT + (long)c * 64 * DDE + (long)d * DDE + h0 + quad * 4) =
        make_short4(bf16_of(v0), bf16_of(v1), bf16_of(v2), bf16_of(v3));
}

// ---------------------------------------------------------------------------
// denoise-2: 32-i tiles, BK=128 (4 iters). Grid (32,32)=1024 blocks,
// 4 blocks/CU. LDS 26.1 KB.  S16[c][i][d] = dW2 @ H[c] + db2  (m=d, n=i)
// ---------------------------------------------------------------------------
__global__ __launch_bounds__(256) void gemm_dn2(
    const short* __restrict__ HT, const float* __restrict__ dW2,
    const float* __restrict__ db2, short* __restrict__ S16)
{
    const int c  = blockIdx.y;
    const int i0 = blockIdx.x * 32;

    __shared__ short Asb[64 * 136];
    __shared__ short Bsb[32 * 136];

    const int t = threadIdx.x, w = t >> 6, lane = t & 63;
    const int ln = lane & 15, quad = lane >> 4;
    const int br = t >> 2, bk = (t & 3) * 32;   // A: 64 rows x 128 bf16
    const int ar = t >> 3, ak = (t & 7) * 16;   // B: 32 rows x 128 fp32

    const short* Ap = HT + (long)c * 64 * DDE + (long)br * DDE + bk;
    const float* Bp = dW2 + (long)(i0 + ar) * DDE + ak;

    floatx4 acc[2] = {};
    short8 sa0 = *(const short8*)(Ap),      sa1 = *(const short8*)(Ap + 8);
    short8 sa2 = *(const short8*)(Ap + 16), sa3 = *(const short8*)(Ap + 24);
    float4 fb0 = *(const float4*)(Bp),      fb1 = *(const float4*)(Bp + 4);
    float4 fb2 = *(const float4*)(Bp + 8),  fb3 = *(const float4*)(Bp + 12);

    for (int k0 = 0; k0 < DDE; k0 += 128) {
        __syncthreads();
        *(short8*)&Asb[br * 136 + bk]      = sa0;
        *(short8*)&Asb[br * 136 + bk + 8]  = sa1;
        *(short8*)&Asb[br * 136 + bk + 16] = sa2;
        *(short8*)&Asb[br * 136 + bk + 24] = sa3;
        *(short8*)&Bsb[ar * 136 + ak]      = cvt8(fb0, fb1);
        *(short8*)&Bsb[ar * 136 + ak + 8]  = cvt8(fb2, fb3);
        __syncthreads();
        const int kn = k0 + 128;
        if (kn < DDE) {
            sa0 = *(const short8*)(Ap + kn);      sa1 = *(const short8*)(Ap + kn + 8);
            sa2 = *(const short8*)(Ap + kn + 16); sa3 = *(const short8*)(Ap + kn + 24);
            fb0 = *(const float4*)(Bp + kn);      fb1 = *(const float4*)(Bp + kn + 4);
            fb2 = *(const float4*)(Bp + kn + 8);  fb3 = *(const float4*)(Bp + kn + 12);
        }
        #pragma unroll
        for (int kc = 0; kc < 4; ++kc) {
            short8 af = *(const short8*)&Asb[(w * 16 + ln) * 136 + kc * 32 + quad * 8];
            #pragma unroll
            for (int j = 0; j < 2; ++j) {
                short8 bf = *(const short8*)&Bsb[(j * 16 + ln) * 136 + kc * 32 + quad * 8];
                acc[j] = __builtin_amdgcn_mfma_f32_16x16x32_bf16(af, bf, acc[j], 0, 0, 0);
            }
        }
    }

    // C[m=d][n=i]: d = w*16 + quad*4 + r, i = i0 + j*16 + ln
    const int d0 = w * 16 + quad * 4;
    #pragma unroll
    for (int j = 0; j < 2; ++j) {
        const int i = i0 + j * 16 + ln;
        const float bb = db2[i];
        short t0 = bf16_of(acc[j][0] + bb);
        short t1 = bf16_of(acc[j][1] + bb);
        short t2 = bf16_of(acc[j][2] + bb);
        short t3 = bf16_of(acc[j][3] + bb);
        *(short4*)(S16 + ((long)c * INTRA + i) * DCP + d0) = make_short4(t0, t1, t2, t3);
    }
}

// ---------------------------------------------------------------------------
// fuse: phase 1 gathers rows once and caches them in swizzled LDS G;
// phase 2 MFMA matvec reads A-frags from G (no second global gather).
// G[l][d]: 16B block cb (=d-bytes/16) stored at column block (cb ^ (l&7)).
// LDS total 72,832 B -> 2 blocks/CU.
// ---------------------------------------------------------------------------
__global__ __launch_bounds__(256) void fuse_kernel(
    const float* __restrict__ x_loc, const int* __restrict__ indices,
    const short* __restrict__ S16, const float* __restrict__ lamda1,
    const float* __restrict__ lamda2, float* __restrict__ out)
{
    const int c = blockIdx.x;
    const int b = blockIdx.y;

    __shared__ __align__(16) short smem[36416];
    short* G   = smem;                                   // 512*64 = 32768
    float* xs  = (float*)(smem + 32768);                 // 512 f
    int*   idx = (int*)(smem + 33792);                   // 512 i
    float (*red)[DCP] = (float(*)[DCP])(smem + 34816);   // 4*64 f
    short* wbf = smem + 35328;                           // 64
    float* ob  = (float*)(smem + 35392);                 // 512 f

    const int t = threadIdx.x;
    const float* xp = x_loc + ((long)b * Cn + c) * Ln;
    const int*   ip = indices + (long)b * Ln;
    ((float2*)xs)[t] = ((const float2*)xp)[t];
    ((int2*)idx)[t]  = ((const int2*)ip)[t];
    __syncthreads();

    const short* Sc = S16 + (long)c * INTRA * DCP;
    const int lane = t & 63;
    const int w    = t >> 6;
    const int r    = lane >> 4;    // row-in-group 0..3
    const int dg   = lane & 15;    // d-group: d = dg*4..dg*4+3

    // Phase 1: gather + |x-g| partial sums; also cache g into swizzled G.
    float s0 = 0.f, s1 = 0.f, s2 = 0.f, s3 = 0.f;
    #pragma unroll 4
    for (int i = 0; i < 32; ++i) {
        const int l   = w * 128 + i * 4 + r;
        const int row = idx[l];
        short4 g = *(const short4*)(Sc + (long)row * DCP + dg * 4);
        // swizzled store: shorts offset = l*64 + ((dg>>1)^(l&7))*8 + (dg&1)*4
        *(short4*)&G[l * 64 + (((dg >> 1) ^ (l & 7)) * 8) + (dg & 1) * 4] = g;
        const float x = xs[l];
        s0 += fabsf(x - f_of_bf16(g.x));
        s1 += fabsf(x - f_of_bf16(g.y));
        s2 += fabsf(x - f_of_bf16(g.z));
        s3 += fabsf(x - f_of_bf16(g.w));
    }
    s0 += __shfl_xor(s0, 16); s0 += __shfl_xor(s0, 32);
    s1 += __shfl_xor(s1, 16); s1 += __shfl_xor(s1, 32);
    s2 += __shfl_xor(s2, 16); s2 += __shfl_xor(s2, 32);
    s3 += __shfl_xor(s3, 16); s3 += __shfl_xor(s3, 32);
    if (lane < 16) {
        red[w][dg * 4 + 0] = s0;
        red[w][dg * 4 + 1] = s1;
        red[w][dg * 4 + 2] = s2;
        red[w][dg * 4 + 3] = s3;
    }
    __syncthreads();

    // Softmax over d (wave 0)
    if (t < DCP) {
        float sc = red[0][t] + red[1][t] + red[2][t] + red[3][t];
        sc = -sc * (SCALEF * 0.044194173824159216f);  // * 1/sqrt(512)
        float m = sc;
        #pragma unroll
        for (int o = 32; o > 0; o >>= 1) m = fmaxf(m, __shfl_xor(m, o));
        float e = __expf(sc - m);
        float ssum = e;
        #pragma unroll
        for (int o = 32; o > 0; o >>= 1) ssum += __shfl_xor(ssum, o);
        wbf[t] = bf16_of(e / ssum);
    }
    __syncthreads();

    // Phase 2: out[l] = sum_d w[d]*G[l][d] via MFMA; A-frags from swizzled G.
    const int quad = lane >> 4;
    const int ln16 = lane & 15;
    short8 bw0 = *(const short8*)&wbf[quad * 8];
    short8 bw1 = *(const short8*)&wbf[32 + quad * 8];

    #pragma unroll
    for (int mt = 0; mt < 8; ++mt) {
        const int mrow = w * 128 + mt * 16 + ln16;
        short8 a0 = *(const short8*)&G[mrow * 64 + ((quad ^ (mrow & 7)) * 8)];
        short8 a1 = *(const short8*)&G[mrow * 64 + (((4 + quad) ^ (mrow & 7)) * 8)];
        floatx4 acc = {};
        acc = __builtin_amdgcn_mfma_f32_16x16x32_bf16(a0, bw0, acc, 0, 0, 0);
        acc = __builtin_amdgcn_mfma_f32_16x16x32_bf16(a1, bw1, acc, 0, 0, 0);
        if (ln16 == 0) {
            const int l0 = w * 128 + mt * 16 + quad * 4;
            ob[l0 + 0] = acc[0];
            ob[l0 + 1] = acc[1];
            ob[l0 + 2] = acc[2];
            ob[l0 + 3] = acc[3];
        }
    }
    __syncthreads();

    // Final blend, coalesced
    const float lam1 = 1.f / (1.f + __expf(-lamda1[c]));
    #pragma unroll
    for (int j = 0; j < 2; ++j) {
        const int l = t + j * 256;
        const float lam = lam1 * (1.f / (1.f + __expf(-lamda2[l])));
        out[((long)b * Cn + c) * Ln + l] = ob[l] * lam + xs[l] * (1.f - lam);
    }
}

// ---------------------------------------------------------------------------
// Launch: 4 dispatches, all 1024 blocks.
// ---------------------------------------------------------------------------
extern "C" void kernel_launch(void* const* d_in, const int* in_sizes, int n_in,
                              void* d_out, int out_size, void* d_ws, size_t ws_size,
                              hipStream_t stream)
{
    const float* x_loc   = (const float*)d_in[0];
    const int*   indices = (const int*)d_in[1];
    const float* map_raw = (const float*)d_in[2];
    const float* cW1     = (const float*)d_in[3];
    const float* cb1     = (const float*)d_in[4];
    const float* cW2     = (const float*)d_in[5];
    const float* cb2     = (const float*)d_in[6];
    const float* dW1     = (const float*)d_in[7];
    const float* db1     = (const float*)d_in[8];
    const float* dW2     = (const float*)d_in[9];
    const float* db2     = (const float*)d_in[10];
    const float* lamda1  = (const float*)d_in[11];
    const float* lamda2  = (const float*)d_in[12];
    float* out = (float*)d_out;

    short* wsS = (short*)d_ws;
    short* M1T = wsS;                 // 32*64*1024 bf16
    short* HT  = M1T + 2097152;       // 32*64*512
    short* S16 = HT + 1048576;        // 32*1024*64

    compress_fused<<<dim3(INTRA / 32, Cn), 256, 0, stream>>>(
        map_raw, cW1, cb1, cW2, cb2, M1T);

    gemm_dn1<<<dim3(DDE / 16, Cn), 256, 0, stream>>>(
        dW1, M1T, db1, HT);

    gemm_dn2<<<dim3(INTRA / 32, Cn), 256, 0, stream>>>(
        HT, dW2, db2, S16);

    fuse_kernel<<<dim3(Cn, Bn), 256, 0, stream>>>(
        x_loc, indices, S16, lamda1, lamda2, out);
}